// Round 1
// baseline (830.647 us; speedup 1.0000x reference)
//
#include <hip/hip_runtime.h>
#include <math.h>

#define N_NODES 100000
#define E_EDGES 800000

__global__ __launch_bounds__(256) void vae_fused(
    const float* __restrict__ x,
    const int* __restrict__ edge_src,
    const int* __restrict__ edge_dst,
    const float* __restrict__ eps,
    const float* __restrict__ W_agg, const float* __restrict__ b_agg,
    const float* __restrict__ W_fus, const float* __restrict__ b_fus,
    const float* __restrict__ W1,  const float* __restrict__ b1,
    const float* __restrict__ W21, const float* __restrict__ b21,
    const float* __restrict__ W22, const float* __restrict__ b22,
    const float* __restrict__ W3,  const float* __restrict__ b3,
    const float* __restrict__ W4,  const float* __restrict__ b4,
    float* __restrict__ out)
{
    const int wave = (int)((blockIdx.x * blockDim.x + threadIdx.x) >> 6);
    const int lane = (int)(threadIdx.x & 63);
    if (wave >= N_NODES) return;
    const int node = wave;

    // ---- find edge range for this node (edge_dst is sorted ascending) ----
    int lo = 0, hi = E_EDGES;
    while (lo < hi) { int mid = (lo + hi) >> 1; if (edge_dst[mid] < node) lo = mid + 1; else hi = mid; }
    const int start = lo;
    hi = E_EDGES;
    while (lo < hi) { int mid = (lo + hi) >> 1; if (edge_dst[mid] < node + 1) lo = mid + 1; else hi = mid; }
    const int end = lo;

    // ---- segment mean of x[src] ----
    float sum = 0.0f;
    for (int e = start; e < end; ++e) {
        const int src = edge_src[e];
        sum += x[(long)src * 64 + lane];
    }
    const float cnt = (float)(end - start);
    const float avg = sum / fmaxf(cnt, 1.0f);

    const float xv = x[(long)node * 64 + lane];

    // ---- ne = relu(avg @ W_agg + b_agg) ----
    float ne = b_agg[lane];
    #pragma unroll
    for (int k = 0; k < 64; ++k) {
        const float a = __shfl(avg, k, 64);
        ne = fmaf(a, W_agg[k * 64 + lane], ne);
    }
    ne = fmaxf(ne, 0.0f);

    // ---- xf = relu([x, ne] @ W_fus + b_fus) ----
    float xf = b_fus[lane];
    #pragma unroll
    for (int k = 0; k < 64; ++k) {
        const float a = __shfl(xv, k, 64);
        xf = fmaf(a, W_fus[k * 64 + lane], xf);
    }
    #pragma unroll
    for (int k = 0; k < 64; ++k) {
        const float a = __shfl(ne, k, 64);
        xf = fmaf(a, W_fus[(64 + k) * 64 + lane], xf);
    }
    xf = fmaxf(xf, 0.0f);

    // ---- h1 = relu(xf @ W1 + b1) ----
    float h1 = b1[lane];
    #pragma unroll
    for (int k = 0; k < 64; ++k) {
        const float a = __shfl(xf, k, 64);
        h1 = fmaf(a, W1[k * 64 + lane], h1);
    }
    h1 = fmaxf(h1, 0.0f);

    // ---- mu, logvar (16-wide, replicated across 4 lane groups) ----
    const int j = lane & 15;
    float mu = b21[j];
    float lv = b22[j];
    #pragma unroll
    for (int k = 0; k < 64; ++k) {
        const float a = __shfl(h1, k, 64);
        mu = fmaf(a, W21[k * 16 + j], mu);
        lv = fmaf(a, W22[k * 16 + j], lv);
    }

    // ---- z = mu + eps * exp(0.5*logvar) ----
    const float z = mu + eps[(long)node * 16 + j] * expf(0.5f * lv);

    // ---- h3 = relu(z @ W3 + b3); z[k] lives at lane k (k<16) ----
    float h3 = b3[lane];
    #pragma unroll
    for (int k = 0; k < 16; ++k) {
        const float a = __shfl(z, k, 64);
        h3 = fmaf(a, W3[k * 64 + lane], h3);
    }
    h3 = fmaxf(h3, 0.0f);

    // ---- recon = sigmoid(h3 @ W4 + b4) ----
    float pre = b4[lane];
    #pragma unroll
    for (int k = 0; k < 64; ++k) {
        const float a = __shfl(h3, k, 64);
        pre = fmaf(a, W4[k * 64 + lane], pre);
    }
    const float recon = 1.0f / (1.0f + expf(-pre));

    // ---- outputs: recon [N,64] | mu [N,16] | logvar [N,16] ----
    out[(long)node * 64 + lane] = recon;
    if (lane < 16) {
        out[(long)N_NODES * 64 + (long)node * 16 + j] = mu;
        out[(long)N_NODES * 64 + (long)N_NODES * 16 + (long)node * 16 + j] = lv;
    }
}

extern "C" void kernel_launch(void* const* d_in, const int* in_sizes, int n_in,
                              void* d_out, int out_size, void* d_ws, size_t ws_size,
                              hipStream_t stream) {
    const float* x        = (const float*)d_in[0];
    const int*   edge_src = (const int*)  d_in[1];
    const int*   edge_dst = (const int*)  d_in[2];
    const float* eps      = (const float*)d_in[3];
    const float* W_agg    = (const float*)d_in[4];
    const float* b_agg    = (const float*)d_in[5];
    const float* W_fus    = (const float*)d_in[6];
    const float* b_fus    = (const float*)d_in[7];
    const float* W1       = (const float*)d_in[8];
    const float* b1       = (const float*)d_in[9];
    const float* W21      = (const float*)d_in[10];
    const float* b21      = (const float*)d_in[11];
    const float* W22      = (const float*)d_in[12];
    const float* b22      = (const float*)d_in[13];
    const float* W3       = (const float*)d_in[14];
    const float* b3       = (const float*)d_in[15];
    const float* W4       = (const float*)d_in[16];
    const float* b4       = (const float*)d_in[17];
    float* out = (float*)d_out;

    const int waves_per_block = 256 / 64;                       // 4 nodes per block
    const int grid = (N_NODES + waves_per_block - 1) / waves_per_block;  // 25000
    vae_fused<<<grid, 256, 0, stream>>>(x, edge_src, edge_dst, eps,
                                        W_agg, b_agg, W_fus, b_fus,
                                        W1, b1, W21, b21, W22, b22,
                                        W3, b3, W4, b4, out);
}